// Round 2
// baseline (50766.888 us; speedup 1.0000x reference)
//
#include <hip/hip_runtime.h>
#include <hip/hip_bf16.h>

#define TSTEPS 256
#define BATCH  64
#define NINP   64
#define NHID   4096
#define NGATE  (4 * NHID)        // 16384
#define KDIM   (NINP + NHID)     // 4160
#define NCHUNK (KDIM / 32)       // 130 chunks of 32 k-values
#define NGRP   (NGATE / 16)      // 1024 groups of 16 gate rows
#define NBLK   256               // persistent grid = #CUs

typedef __bf16 bf16x8 __attribute__((ext_vector_type(8)));
typedef float  f32x4  __attribute__((ext_vector_type(4)));
typedef unsigned short ushort_t;

__device__ __forceinline__ ushort_t f2b(float v) {
    __hip_bfloat16 h = __float2bfloat16(v);
    return *reinterpret_cast<ushort_t*>(&h);
}
__device__ __forceinline__ float sigf(float x) { return 1.f / (1.f + expf(-x)); }

// Fragment-linear layout:
//   W'[grp][chunk][lane][8] : lane = q*16 + n holds row (grp*16+n), k = chunk*32 + q*8 .. +8
//   A'[rt ][chunk][lane][8] : lane = q*16 + n holds batch row (rt*16+n), same k packing

// ---- pack [w_ih | w_hh] -> swizzled bf16 W', bias = b_ih + b_hh ----
__global__ void k_convert(const float* __restrict__ w_ih, const float* __restrict__ w_hh,
                          const float* __restrict__ b_ih, const float* __restrict__ b_hh,
                          ushort_t* __restrict__ Wp, float* __restrict__ bias) {
    const int grp = blockIdx.x;                  // 0..1023
    for (int i = threadIdx.x; i < 16 * KDIM; i += 256) {
        int r = i / KDIM;                        // row within group 0..15
        int k = i - r * KDIM;
        int g = grp * 16 + r;                    // gate row 0..16383
        float v = (k < NINP) ? w_ih[(size_t)g * NINP + k]
                             : w_hh[(size_t)g * NHID + (k - NINP)];
        int c = k >> 5, q = (k >> 3) & 3, e = k & 7;
        Wp[((size_t)grp * NCHUNK + c) * 512 + (q * 16 + r) * 8 + e] = f2b(v);
    }
    if (threadIdx.x < 16) {
        int g = grp * 16 + threadIdx.x;
        bias[g] = b_ih[g] + b_hh[g];
    }
}

// ---- init A0' = [emb(tokens[0]) | 0] (swizzled) ----
__global__ void k_init(const int* __restrict__ tokens, const float* __restrict__ emb,
                       ushort_t* __restrict__ A0) {
    int idx = blockIdx.x * 256 + threadIdx.x;
    if (idx < BATCH * KDIM) {
        int b = idx / KDIM, k = idx - b * KDIM;
        float v = (k < NINP) ? emb[tokens[b] * NINP + k] : 0.f;
        int c = k >> 5, q = (k >> 3) & 3, e = k & 7;
        A0[((size_t)(b >> 4) * NCHUNK + c) * 512 + (q * 16 + (b & 15)) * 8 + e] = f2b(v);
    }
}

// ---- persistent LSTM: 16 waves/block, cross-barrier W prefetch ----
__global__ __launch_bounds__(1024, 4)
void k_persist(const ushort_t* __restrict__ Wp, const float* __restrict__ bias,
               ushort_t* __restrict__ A0, ushort_t* __restrict__ A1,
               float* __restrict__ out,
               const int* __restrict__ tokens, const int* __restrict__ seq_len,
               const float* __restrict__ emb, unsigned* __restrict__ bar) {
    const int tid  = threadIdx.x;
    const int wave = tid >> 6;          // 0..15
    const int lane = tid & 63;
    const int bx   = blockIdx.x;
    const int j0   = bx * 16;

    __shared__ float sbuf[BATCH][66];   // cross-wave gate reduction (pad 66)
    __shared__ float creg[BATCH][17];   // persistent cell state, block-private

    for (int i2 = tid; i2 < BATCH * 17; i2 += 1024) (&creg[0][0])[i2] = 0.f;

    const int sl = seq_len[lane];       // this thread's batch row = lane
    float bi[4];                        // bias for this thread's column j0+wave
    #pragma unroll
    for (int g = 0; g < 4; ++g) bi[g] = bias[g * NHID + j0 + wave];

    // K-chunk split: waves 0,1 -> 9 chunks, waves 2..15 -> 8 (sum 130)
    const int cstart = wave * 8 + (wave < 2 ? wave : 2);
    const int NC     = (wave < 2 ? 9 : 8);

    const ushort_t* pw0 = Wp + ((size_t)(0 * 256 + bx) * NCHUNK) * 512 + lane * 8;
    const ushort_t* pw1 = Wp + ((size_t)(1 * 256 + bx) * NCHUNK) * 512 + lane * 8;
    const ushort_t* pw2 = Wp + ((size_t)(2 * 256 + bx) * NCHUNK) * 512 + lane * 8;
    const ushort_t* pw3 = Wp + ((size_t)(3 * 256 + bx) * NCHUNK) * 512 + lane * 8;

    const int eb = bx >> 2;             // distributed emb producer: batch row
    const int ek = (bx & 3) * 16;       //                           k base

    #define LOADW(WD, cc) do {                                            \
        const size_t _o = (size_t)(cc) * 512;                             \
        WD[0] = *reinterpret_cast<const bf16x8*>(pw0 + _o);               \
        WD[1] = *reinterpret_cast<const bf16x8*>(pw1 + _o);               \
        WD[2] = *reinterpret_cast<const bf16x8*>(pw2 + _o);               \
        WD[3] = *reinterpret_cast<const bf16x8*>(pw3 + _o);               \
    } while (0)

    #define LOADA(AD, cc) do {                                            \
        const size_t _o = (size_t)(cc) * 512;                             \
        AD[0] = *reinterpret_cast<const bf16x8*>(pa0 + _o);               \
        AD[1] = *reinterpret_cast<const bf16x8*>(pa1 + _o);               \
        AD[2] = *reinterpret_cast<const bf16x8*>(pa2 + _o);               \
        AD[3] = *reinterpret_cast<const bf16x8*>(pa3 + _o);               \
    } while (0)

    #define DOMFMA(WD, AD) do {                                           \
        _Pragma("unroll")                                                 \
        for (int _rt = 0; _rt < 4; ++_rt) {                               \
            _Pragma("unroll")                                             \
            for (int _gt = 0; _gt < 4; ++_gt)                             \
                acc[_rt][_gt] = __builtin_amdgcn_mfma_f32_16x16x32_bf16(  \
                    AD[_rt], WD[_gt], acc[_rt][_gt], 0, 0, 0);            \
        }                                                                 \
    } while (0)

    // W double-buffer lives ACROSS steps: prefetched pre-barrier (W is immutable)
    bf16x8 wA[4], wB[4], xA[4], xB[4];
    LOADW(wA, cstart);
    LOADW(wB, cstart + 1);

    for (int t = 0; t < TSTEPS; ++t) {
        ushort_t* Ac = (t & 1) ? A1 : A0;
        ushort_t* An = (t & 1) ? A0 : A1;

        for (int i2 = tid; i2 < BATCH * 66; i2 += 1024) (&sbuf[0][0])[i2] = 0.f;

        const ushort_t* pa0 = Ac + (size_t)(0 * NCHUNK) * 512 + lane * 8;
        const ushort_t* pa1 = Ac + (size_t)(1 * NCHUNK) * 512 + lane * 8;
        const ushort_t* pa2 = Ac + (size_t)(2 * NCHUNK) * 512 + lane * 8;
        const ushort_t* pa3 = Ac + (size_t)(3 * NCHUNK) * 512 + lane * 8;

        f32x4 acc[4][4];
        #pragma unroll
        for (int rt = 0; rt < 4; ++rt)
            #pragma unroll
            for (int gt = 0; gt < 4; ++gt)
                acc[rt][gt] = (f32x4){0.f, 0.f, 0.f, 0.f};

        LOADA(xA, cstart);
        LOADA(xB, cstart + 1);
        int i = 0;
        for (; i + 2 < NC; i += 2) {
            DOMFMA(wA, xA);
            LOADW(wA, cstart + i + 2); LOADA(xA, cstart + i + 2);
            DOMFMA(wB, xB);
            if (i + 3 < NC) { LOADW(wB, cstart + i + 3); LOADA(xB, cstart + i + 3); }
        }
        DOMFMA(wA, xA);
        if ((NC & 1) == 0) DOMFMA(wB, xB);

        __syncthreads();                 // sbuf zeros visible to all waves
        {
            // C/D layout: col = lane&15 (gate col n), row = (lane>>4)*4 + r
            const int n = lane & 15, q = lane >> 4;
            #pragma unroll
            for (int rt = 0; rt < 4; ++rt)
                #pragma unroll
                for (int gt = 0; gt < 4; ++gt)
                    #pragma unroll
                    for (int r = 0; r < 4; ++r)
                        atomicAdd(&sbuf[rt * 16 + q * 4 + r][gt * 16 + n], acc[rt][gt][r]);
        }
        __syncthreads();

        // cell update: thread (wave, lane) handles batch b=lane, col jl=wave (1 each)
        {
            const int b  = lane;
            const int jl = wave;                       // 0..15
            const int j  = j0 + jl;
            float ig = sbuf[b][ 0 + jl] + bi[0];
            float fg = sbuf[b][16 + jl] + bi[1];
            float gg = sbuf[b][32 + jl] + bi[2];
            float og = sbuf[b][48 + jl] + bi[3];
            float cold = creg[b][jl];
            float cn = sigf(fg) * cold + sigf(ig) * tanhf(gg);
            float hn = sigf(og) * tanhf(cn);
            creg[b][jl] = cn;
            if (t == sl - 1) out[b * NHID + j] = cn;   // final feature only
            const int kk = NINP + j;                   // h position in A' k-dim
            const int c = kk >> 5, q2 = (kk >> 3) & 3, e = kk & 7;
            An[((size_t)(b >> 4) * NCHUNK + c) * 512 + (q2 * 16 + (b & 15)) * 8 + e] = f2b(hn);

            // next-step embedding, distributed: 16 values per block
            if (tid < 16 && (t + 1) < TSTEPS) {
                const int k   = ek + tid;
                const int tok = tokens[(t + 1) * BATCH + eb];
                const float v = emb[tok * NINP + k];
                const int c2 = k >> 5, q3 = (k >> 3) & 3, e2 = k & 7;
                An[((size_t)(eb >> 4) * NCHUNK + c2) * 512 + (q3 * 16 + (eb & 15)) * 8 + e2] = f2b(v);
            }
        }

        // prefetch next step's first W chunks BEFORE the barrier:
        // W is immutable, registers survive the fence, loads overlap the spin.
        LOADW(wA, cstart);
        LOADW(wB, cstart + 1);

        // ---- grid barrier: release-arrive, spin, acquire ----
        __syncthreads();                 // all block stores issued+drained
        if (tid == 0) {
            __hip_atomic_fetch_add(bar, 1u, __ATOMIC_RELEASE, __HIP_MEMORY_SCOPE_AGENT);
            const unsigned tgt = (unsigned)(t + 1) * NBLK;
            int guard = 0;
            while (__hip_atomic_load(bar, __ATOMIC_RELAXED, __HIP_MEMORY_SCOPE_AGENT) < tgt) {
                __builtin_amdgcn_s_sleep(2);
                if (++guard > (1 << 20)) break;   // safety valve
            }
        }
        __syncthreads();
        __builtin_amdgcn_fence(__ATOMIC_ACQUIRE, "agent");   // see fresh A writes
    }

    #undef LOADW
    #undef LOADA
    #undef DOMFMA
}

extern "C" void kernel_launch(void* const* d_in, const int* in_sizes, int n_in,
                              void* d_out, int out_size, void* d_ws, size_t ws_size,
                              hipStream_t stream) {
    const int*   tokens  = (const int*)d_in[0];
    const int*   seq_len = (const int*)d_in[1];
    const float* emb     = (const float*)d_in[2];
    const float* w_ih    = (const float*)d_in[3];
    const float* w_hh    = (const float*)d_in[4];
    const float* b_ih    = (const float*)d_in[5];
    const float* b_hh    = (const float*)d_in[6];
    float* out = (float*)d_out;

    char* ws = (char*)d_ws;
    const size_t W_BYTES    = (size_t)NGRP * NCHUNK * 512 * 2;  // 136,314,880
    const size_t BIAS_BYTES = (size_t)NGATE * 4;                // 65,536
    const size_t BAR_BYTES  = 1024;
    const size_t A_BYTES    = (size_t)4 * NCHUNK * 512 * 2;     // 532,480

    ushort_t* Wp   = (ushort_t*)ws;
    float*    bias = (float*)(ws + W_BYTES);
    unsigned* bar  = (unsigned*)(ws + W_BYTES + BIAS_BYTES);
    ushort_t* A0   = (ushort_t*)(ws + W_BYTES + BIAS_BYTES + BAR_BYTES);
    ushort_t* A1   = (ushort_t*)(ws + W_BYTES + BIAS_BYTES + BAR_BYTES + A_BYTES);

    hipMemsetAsync(bar, 0, 8, stream);

    k_convert<<<NGRP, 256, 0, stream>>>(w_ih, w_hh, b_ih, b_hh, Wp, bias);

    int init_elems = BATCH * KDIM;
    k_init<<<(init_elems + 255) / 256, 256, 0, stream>>>(tokens, emb, A0);

    k_persist<<<NBLK, 1024, 0, stream>>>(Wp, bias, A0, A1, out,
                                         tokens, seq_len, emb, bar);
}

// Round 3
// 15776.421 us; speedup vs baseline: 3.2179x; 3.2179x over previous
//
#include <hip/hip_runtime.h>
#include <hip/hip_bf16.h>

#define TSTEPS 256
#define BATCH  64
#define NINP   64
#define NHID   4096
#define NGATE  (4 * NHID)        // 16384
#define KDIM   (NINP + NHID)     // 4160
#define NCHUNK (KDIM / 32)       // 130 chunks of 32 k-values
#define NGRP   (NGATE / 16)      // 1024 groups of 16 gate rows
#define NBLK   512               // 2 blocks per CU

typedef __bf16 bf16x8 __attribute__((ext_vector_type(8)));
typedef float  f32x4  __attribute__((ext_vector_type(4)));
typedef unsigned short ushort_t;

__device__ __forceinline__ ushort_t f2b(float v) {
    __hip_bfloat16 h = __float2bfloat16(v);
    return *reinterpret_cast<ushort_t*>(&h);
}
__device__ __forceinline__ float sigf(float x) { return 1.f / (1.f + expf(-x)); }

// W' group remap for 8-col blocks:
//   group grp = bx*2 + half  (bx 0..511, half 0..1)
//   row r (0..15) of group -> gate type gt = half*2 + (r>>3), hidden col j = bx*8 + (r&7)
//   source gate row g = gt*NHID + j
// Within a group, fragment-linear layout is unchanged:
//   Wp[(grp*NCHUNK + c)*512 + (q*16 + r)*8 + e],  k = c*32 + q*8 + e
// A' layout unchanged from prior rounds.

__global__ void k_convert(const float* __restrict__ w_ih, const float* __restrict__ w_hh,
                          const float* __restrict__ b_ih, const float* __restrict__ b_hh,
                          ushort_t* __restrict__ Wp, float* __restrict__ bias) {
    const int grp  = blockIdx.x;                 // 0..1023
    const int bxo  = grp >> 1;
    const int half = grp & 1;
    for (int i = threadIdx.x; i < 16 * KDIM; i += 256) {
        int r = i / KDIM;                        // row within group 0..15
        int k = i - r * KDIM;
        int gt = half * 2 + (r >> 3);
        int j  = bxo * 8 + (r & 7);
        int g  = gt * NHID + j;                  // gate row 0..16383
        float v = (k < NINP) ? w_ih[(size_t)g * NINP + k]
                             : w_hh[(size_t)g * NHID + (k - NINP)];
        int c = k >> 5, q = (k >> 3) & 3, e = k & 7;
        Wp[((size_t)grp * NCHUNK + c) * 512 + (q * 16 + r) * 8 + e] = f2b(v);
    }
    if (threadIdx.x < 16) {
        int r  = threadIdx.x;
        int gt = half * 2 + (r >> 3);
        int j  = bxo * 8 + (r & 7);
        int g  = gt * NHID + j;
        bias[g] = b_ih[g] + b_hh[g];
    }
}

// ---- init A0' = [emb(tokens[0]) | 0] (swizzled), c = 0 ----
__global__ void k_init(const int* __restrict__ tokens, const float* __restrict__ emb,
                       ushort_t* __restrict__ A0, float* __restrict__ cbuf) {
    int idx = blockIdx.x * 256 + threadIdx.x;
    if (idx < BATCH * KDIM) {
        int b = idx / KDIM, k = idx - b * KDIM;
        float v = (k < NINP) ? emb[tokens[b] * NINP + k] : 0.f;
        int c = k >> 5, q = (k >> 3) & 3, e = k & 7;
        A0[((size_t)(b >> 4) * NCHUNK + c) * 512 + (q * 16 + (b & 15)) * 8 + e] = f2b(v);
    }
    if (idx < BATCH * NHID) cbuf[idx] = 0.f;
}

// ---- one LSTM step: 512 blocks x 512 threads (2 blocks/CU, 16 waves/CU) ----
// block bx owns 8 hidden cols (j0 = bx*8) x 4 gate types via 2 MFMA N-tiles.
__global__ __launch_bounds__(512, 4)
void k_step(int t, const ushort_t* __restrict__ Wp, const float* __restrict__ bias,
            const ushort_t* __restrict__ Ac, ushort_t* __restrict__ An,
            float* __restrict__ cbuf, float* __restrict__ out,
            const int* __restrict__ tokens, const int* __restrict__ seq_len,
            const float* __restrict__ emb) {
    const int tid  = threadIdx.x;
    const int wave = tid >> 6;          // 0..7
    const int lane = tid & 63;
    const int bx   = blockIdx.x;
    const int j0   = bx * 8;

    __shared__ float sbuf[BATCH][34];   // [batch][gt2*16 + n], pad to 34

    for (int i2 = tid; i2 < BATCH * 34; i2 += 512) (&sbuf[0][0])[i2] = 0.f;

    // K-chunk split: waves 0,1 -> 17 chunks, waves 2..7 -> 16 (sum 130)
    const int cstart = wave * 16 + (wave < 2 ? wave : 2);
    const int NC     = (wave < 2 ? 17 : 16);

    const ushort_t* pw0 = Wp + ((size_t)(bx * 2 + 0) * NCHUNK) * 512 + lane * 8;
    const ushort_t* pw1 = Wp + ((size_t)(bx * 2 + 1) * NCHUNK) * 512 + lane * 8;
    const ushort_t* pa0 = Ac + ((size_t)0 * NCHUNK) * 512 + lane * 8;
    const ushort_t* pa1 = Ac + ((size_t)1 * NCHUNK) * 512 + lane * 8;
    const ushort_t* pa2 = Ac + ((size_t)2 * NCHUNK) * 512 + lane * 8;
    const ushort_t* pa3 = Ac + ((size_t)3 * NCHUNK) * 512 + lane * 8;

    f32x4 acc[4][2];                    // [rt batch-tile][gt2]
    #pragma unroll
    for (int rt = 0; rt < 4; ++rt)
        #pragma unroll
        for (int g2 = 0; g2 < 2; ++g2)
            acc[rt][g2] = (f32x4){0.f, 0.f, 0.f, 0.f};

    #define LOADW(WD, cc) do {                                            \
        const size_t _o = (size_t)(cc) * 512;                             \
        WD[0] = *reinterpret_cast<const bf16x8*>(pw0 + _o);               \
        WD[1] = *reinterpret_cast<const bf16x8*>(pw1 + _o);               \
    } while (0)
    #define LOADA(AD, cc) do {                                            \
        const size_t _o = (size_t)(cc) * 512;                             \
        AD[0] = *reinterpret_cast<const bf16x8*>(pa0 + _o);               \
        AD[1] = *reinterpret_cast<const bf16x8*>(pa1 + _o);               \
        AD[2] = *reinterpret_cast<const bf16x8*>(pa2 + _o);               \
        AD[3] = *reinterpret_cast<const bf16x8*>(pa3 + _o);               \
    } while (0)
    #define DOMFMA(WD, AD) do {                                           \
        _Pragma("unroll")                                                 \
        for (int _rt = 0; _rt < 4; ++_rt) {                               \
            _Pragma("unroll")                                             \
            for (int _g2 = 0; _g2 < 2; ++_g2)                             \
                acc[_rt][_g2] = __builtin_amdgcn_mfma_f32_16x16x32_bf16(  \
                    AD[_rt], WD[_g2], acc[_rt][_g2], 0, 0, 0);            \
        }                                                                 \
    } while (0)

    // depth-2 ping-pong, no register rotation
    bf16x8 wA[2], wB[2], xA[4], xB[4];
    LOADW(wA, cstart);        LOADA(xA, cstart);
    LOADW(wB, cstart + 1);    LOADA(xB, cstart + 1);
    int i = 0;
    for (; i + 2 < NC; i += 2) {
        DOMFMA(wA, xA);
        LOADW(wA, cstart + i + 2); LOADA(xA, cstart + i + 2);
        DOMFMA(wB, xB);
        if (i + 3 < NC) { LOADW(wB, cstart + i + 3); LOADA(xB, cstart + i + 3); }
    }
    DOMFMA(wA, xA);
    if ((NC & 1) == 0) DOMFMA(wB, xB);
    #undef LOADW
    #undef LOADA
    #undef DOMFMA

    __syncthreads();                    // sbuf zeros visible
    {
        // C/D layout: col n = lane&15 (group row), row = (lane>>4)*4 + r (batch)
        const int n = lane & 15, q = lane >> 4;
        #pragma unroll
        for (int rt = 0; rt < 4; ++rt)
            #pragma unroll
            for (int g2 = 0; g2 < 2; ++g2)
                #pragma unroll
                for (int r = 0; r < 4; ++r)
                    atomicAdd(&sbuf[rt * 16 + q * 4 + r][g2 * 16 + n], acc[rt][g2][r]);
    }
    __syncthreads();

    // cell update: thread (wave, lane) -> batch b=lane, local col jl=wave (0..7)
    {
        const int b  = lane;
        const int jl = wave;
        const int j  = j0 + jl;
        const int sl = seq_len[b];
        // group row decode: i-gate at n=jl (half0), f at n=8+jl (half0),
        //                   g at n=jl (half1),  o at n=8+jl (half1)
        float ig = sbuf[b][ 0 + jl] + bias[           j];
        float fg = sbuf[b][ 8 + jl] + bias[    NHID + j];
        float gg = sbuf[b][16 + jl] + bias[2 * NHID + j];
        float og = sbuf[b][24 + jl] + bias[3 * NHID + j];
        int cidx = b * NHID + j;
        float cold = cbuf[cidx];
        float cn = sigf(fg) * cold + sigf(ig) * tanhf(gg);
        float hn = sigf(og) * tanhf(cn);
        cbuf[cidx] = cn;
        if (t == sl - 1) out[cidx] = cn;           // final feature only
        const int kk = NINP + j;                   // h position in A' k-dim
        const int c = kk >> 5, q2 = (kk >> 3) & 3, e = kk & 7;
        An[((size_t)(b >> 4) * NCHUNK + c) * 512 + (q2 * 16 + (b & 15)) * 8 + e] = f2b(hn);

        // next-step embedding, distributed: 8 values per block
        if (tid < 8 && (t + 1) < TSTEPS) {
            const int eb  = bx >> 3;               // batch row
            const int k   = (bx & 7) * 8 + tid;    // k index 0..63
            const int tok = tokens[(t + 1) * BATCH + eb];
            const float v = emb[tok * NINP + k];
            const int c2 = k >> 5, q3 = (k >> 3) & 3, e2 = k & 7;
            An[((size_t)(eb >> 4) * NCHUNK + c2) * 512 + (q3 * 16 + (eb & 15)) * 8 + e2] = f2b(v);
        }
    }
}

extern "C" void kernel_launch(void* const* d_in, const int* in_sizes, int n_in,
                              void* d_out, int out_size, void* d_ws, size_t ws_size,
                              hipStream_t stream) {
    const int*   tokens  = (const int*)d_in[0];
    const int*   seq_len = (const int*)d_in[1];
    const float* emb     = (const float*)d_in[2];
    const float* w_ih    = (const float*)d_in[3];
    const float* w_hh    = (const float*)d_in[4];
    const float* b_ih    = (const float*)d_in[5];
    const float* b_hh    = (const float*)d_in[6];
    float* out = (float*)d_out;

    char* ws = (char*)d_ws;
    const size_t W_BYTES    = (size_t)NGRP * NCHUNK * 512 * 2;  // 136,314,880
    const size_t BIAS_BYTES = (size_t)NGATE * 4;                // 65,536
    const size_t C_BYTES    = (size_t)BATCH * NHID * 4;         // 1,048,576
    const size_t A_BYTES    = (size_t)4 * NCHUNK * 512 * 2;     // 532,480

    ushort_t* Wp   = (ushort_t*)ws;
    float*    bias = (float*)(ws + W_BYTES);
    float*    cbuf = (float*)(ws + W_BYTES + BIAS_BYTES);
    ushort_t* A0   = (ushort_t*)(ws + W_BYTES + BIAS_BYTES + C_BYTES);
    ushort_t* A1   = (ushort_t*)(ws + W_BYTES + BIAS_BYTES + C_BYTES + A_BYTES);

    k_convert<<<NGRP, 256, 0, stream>>>(w_ih, w_hh, b_ih, b_hh, Wp, bias);

    int init_elems = BATCH * KDIM;
    k_init<<<(init_elems + 255) / 256, 256, 0, stream>>>(tokens, emb, A0, cbuf);

    for (int t = 0; t < TSTEPS; ++t) {
        ushort_t* Acur  = (t & 1) ? A1 : A0;
        ushort_t* Anext = (t & 1) ? A0 : A1;
        k_step<<<NBLK, 512, 0, stream>>>(t, Wp, bias, Acur, Anext, cbuf, out,
                                         tokens, seq_len, emb);
    }
}